// Round 20
// baseline (129.445 us; speedup 1.0000x reference)
//
#include <hip/hip_runtime.h>
#include <cstdint>
#include <cstddef>

using u32 = unsigned int;
using u64 = unsigned long long;

typedef int v4i  __attribute__((ext_vector_type(4)));
typedef int v16i __attribute__((ext_vector_type(16)));

#define EPSV 1e-5f
#define MFMA_I8(A, B, C) __builtin_amdgcn_mfma_i32_32x32x32_i8((A), (B), (C), 0, 0, 0)

// ---------------------------------------------------------------------------
// Kernel 1: weight prep. Wsgn[conv][co][p][c] = sign(w - mean);
// SC4 = (alpha, scale, shift, 0), IEEE ops in the reference's exact order.
// ---------------------------------------------------------------------------
__global__ void prep_weights(const float* __restrict__ w1, const float* __restrict__ w2,
                             const float* __restrict__ a1, const float* __restrict__ g1,
                             const float* __restrict__ b1, const float* __restrict__ m1,
                             const float* __restrict__ v1,
                             const float* __restrict__ a2, const float* __restrict__ g2,
                             const float* __restrict__ b2, const float* __restrict__ m2,
                             const float* __restrict__ v2,
                             unsigned char* __restrict__ Wsgn, float4* __restrict__ SC4)
{
    const int co   = blockIdx.x;
    const int conv = blockIdx.y;
    const int c    = threadIdx.x;
    const float* w = conv ? w2 : w1;

    float wv[9];
    const float* wp = w + ((size_t)co * 256 + c) * 9;
    float s = 0.f;
#pragma unroll
    for (int p = 0; p < 9; ++p) { wv[p] = wp[p]; s += wv[p]; }

    __shared__ float red[256];
    red[c] = s;
    __syncthreads();
    for (int off = 128; off > 0; off >>= 1) {
        if (c < off) red[c] += red[c + off];
        __syncthreads();
    }
    const float mean = __fdiv_rn(red[0], 2304.0f);

    unsigned char* wrow = Wsgn + ((size_t)(conv * 256 + co) * 9) * 256;
#pragma unroll
    for (int p = 0; p < 9; ++p)
        wrow[p * 256 + c] = (wv[p] > mean) ? 0x01u : 0xFFu;

    if (c == 0) {
        const float alpha = conv ? a2[co] : a1[co];
        const float gamma = conv ? g2[co] : g1[co];
        const float beta  = conv ? b2[co] : b1[co];
        const float mu    = conv ? m2[co] : m1[co];
        const float var   = conv ? v2[co] : v1[co];
        const float sq    = __fsqrt_rn(__fadd_rn(var, EPSV));
        const float scale = __fdiv_rn(gamma, sq);
        const float shift = __fsub_rn(beta, __fdiv_rn(__fmul_rn(mu, gamma), sq));
        SC4[conv * 256 + co] = make_float4(alpha, scale, shift, 0.f);
    }
}

// ---------------------------------------------------------------------------
// Kernel 2: B fragments in exact mfma_i32_32x32x32_i8 operand order.
// Frag f = conv*576 + g*72 + k. Lane l: B[k=(l>>5)*16+j][n=l&31].
// ---------------------------------------------------------------------------
__global__ void build_bfrag(const unsigned char* __restrict__ Wsgn, uint4* __restrict__ Bf)
{
    const int f    = blockIdx.x;           // 0..1151
    const int lane = threadIdx.x;          // 0..63
    const int conv = f / 576;
    const int rem  = f % 576;
    const int g    = rem / 72;
    const int p    = (rem % 72) / 8;
    const int cb   = rem % 8;
    const int co   = g * 32 + (lane & 31);
    const unsigned char* src = Wsgn + ((size_t)(conv * 256 + co) * 9 + p) * 256
                                    + cb * 32 + (lane >> 5) * 16;
    Bf[(size_t)f * 64 + lane] = *(const uint4*)src;
}

// ---------------------------------------------------------------------------
// Kernel 3: binarize x -> packed bits. A[n][pixel][j], j = chan/32.
// ---------------------------------------------------------------------------
__global__ void binarize_x(const float* __restrict__ x, u32* __restrict__ A1)
{
    const int n = blockIdx.x >> 3;
    const int j = blockIdx.x & 7;
    const int p = threadIdx.x;
    const float* xp = x + (((size_t)n * 256 + j * 32) * 1024) + p;
    u32 bits = 0;
#pragma unroll
    for (int k = 0; k < 32; ++k) {
        float v = xp[(size_t)k * 1024];
        bits |= (v > 0.f ? 1u : 0u) << k;
    }
    A1[((size_t)n * 1024 + p) * 8 + j] = bits;
}

__device__ __forceinline__ u32 expand4(u32 x)
{
    u32 r;
    r  = ((x & 1u) ? 0x00000001u : 0x000000FFu);
    r |= ((x & 2u) ? 0x00000100u : 0x0000FF00u);
    r |= ((x & 4u) ? 0x00010000u : 0x00FF0000u);
    r |= ((x & 8u) ? 0x01000000u : 0xFF000000u);
    return r;
}

__device__ __forceinline__ void glds16(const void* g, void* l)
{
    __builtin_amdgcn_global_load_lds(
        (const __attribute__((address_space(1))) void*)g,
        (__attribute__((address_space(3))) void*)l, 16, 0, 0);
}

// ---------------------------------------------------------------------------
// Kernel 4/5: binary conv as i8 MFMA GEMM — wide-phase 8-wave schedule.
//
// R19 insight: every prior variant ran 8 MFMA per barrier-pair and ~1 phase
// of load cover, and ALL plateaued at 28.6% of the MFMA floor — exactly the
// documented 2-phase-regime ceiling (m233: 28.3%). This version matches the
// m201 template's ratios: 16 MFMA per barrier-pair (phase = 2 K-steps) and
// B staged 2 phases ahead (counted vmcnt(8)); A read 1 phase ahead into an
// alternating named register set (counted lgkmcnt(8) keeps them in flight
// across the MFMA cluster). RAW s_barrier only (no drain).
//
// Phase ph (0..35), per wave:
//   [4 glds B(ph+2) -> ring slot (ph+2)&3]  vmcnt(8)+SB
//   [4 ds_read B(ph)] [8 ds_read A(ph+1) -> alt set]
//   s_barrier   lgkmcnt(8)+SB   setprio1  16 MFMA(A(ph),B(ph))  setprio0
//   s_barrier
// lgkm FIFO at the wait: [prevA 8][thisB 4][thisA 8] -> count 8 drains
// prevA+thisB exactly. Ring slot overwrite safe: writer passed the barrier
// that guarantees the twin drained its reads (2-barrier/phase skew bound).
// vmcnt is per-wave; the wm-twin writes identical bytes (idempotent).
//
// Block: 512 thr = 8 waves; M=256 (8 rows x 32 cols), N=256, 1 block/CU.
// Wave (wm=w>>2, wn=w&3): rows y0+4wm..+3, groups 2wn,2wn+1 -> 8 v16i accs.
// Grid 256 (64 n x 4 yocts), bijective XCD swizzle (256%8==0).
// LDS 152,576 B: A [c16 16][row 10][col 34] 16B cells (87,040, halo zeroed)
// + B ring 4 slots x 16,384 (slot: wn*4096 + ks*2048 + grp*1024 + lane*16).
// ds_reads conflict-free (R6-R19: 0).
//
// A: m(=x)=l&31, k=(l>>5)*16+j ; B: n(=co)=l&31 ; C/D: n=l&31,
// m=(reg&3)+8*(reg>>2)+4*(l>>5)   [R5-R19 HW-verified].
//
// CONV==1: t=(dot*alpha)*scale+shift; packed sign bits via __ballot.
// CONV==2: per-row LDS transpose ep[x][co] (pad 257) -> coalesced
//          clamp(t + X) float4 stores.  (Epilogues verbatim from R15, passed.)
// ---------------------------------------------------------------------------
template<int CONV>
__global__ __launch_bounds__(512, 2)
void conv_mfma(const u32* __restrict__ A_in, const v4i* __restrict__ Bf,
               const float4* __restrict__ SC4, const float* __restrict__ X,
               u32* __restrict__ A_out, float* __restrict__ OUT)
{
    const int logical = (blockIdx.x & 7) * 32 + (blockIdx.x >> 3);
    const int n    = logical >> 2;
    const int yo   = logical & 3;
    const int y0   = yo * 8;
    const int tid  = threadIdx.x;
    const int wave = tid >> 6;          // 0..7
    const int lane = tid & 63;
    const int wm   = wave >> 2;         // 0/1: rows y0+4wm .. +3
    const int wn   = wave & 3;          // 0..3: groups 2wn, 2wn+1
    const int col0 = lane & 31;
    const int g0   = wn * 2;

    __shared__ alignas(16) unsigned char lds[152576];

    const int fbias = (CONV == 2) ? 576 : 0;
    const char* bsrcA = (const char*)Bf + (((size_t)(fbias + g0 * 72)) << 10)
                        + (size_t)lane * 16;
    const char* bsrcB = bsrcA + (72u << 10);          // group g0+1

    // prologue: stage B phases 0,1 -> ring slots 0,1 (8 glds; syncthreads drains)
#pragma unroll
    for (int pf = 0; pf < 2; ++pf) {
        unsigned char* d = lds + 87040 + pf * 16384 + wn * 4096;
        const size_t k0 = (size_t)(2 * pf) << 10;
        const size_t k1 = (size_t)(2 * pf + 1) << 10;
        glds16(bsrcA + k0, d);
        glds16(bsrcB + k0, d + 1024);
        glds16(bsrcA + k1, d + 2048);
        glds16(bsrcB + k1, d + 3072);
    }

    // stage A tile: [c16][row 0..9][col 0..33], halo (row OR col OOB) -> 0
    for (int s = tid; s < 5440; s += 512) {
        const int colv = s % 34;
        const int rest = s / 34;
        const int r    = rest % 10;
        const int c16  = rest / 10;
        const int iy   = y0 - 1 + r;
        const int ix   = colv - 1;
        u32 d0 = 0, d1 = 0, d2 = 0, d3 = 0;
        if ((unsigned)iy < 32u && (unsigned)ix < 32u) {
            const u32 wrd = A_in[((size_t)n * 1024 + iy * 32 + ix) * 8 + (c16 >> 1)];
            const u32 h = (wrd >> ((c16 & 1) * 16)) & 0xFFFFu;
            d0 = expand4(h);
            d1 = expand4(h >> 4);
            d2 = expand4(h >> 8);
            d3 = expand4(h >> 12);
        }
        *(uint4*)(lds + (size_t)s * 16) = make_uint4(d0, d1, d2, d3);
    }

    const int bias2 = (CONV == 2) ? 256 : 0;
    const float4 scA = SC4[bias2 + (g0 + 0) * 32 + col0];
    const float4 scB = SC4[bias2 + (g0 + 1) * 32 + col0];

    __syncthreads();   // A tile + prologue B visible; all counters drained

    const v16i Z  = {0,0,0,0,0,0,0,0,0,0,0,0,0,0,0,0};
    v16i c0a = Z, c0b = Z, c1a = Z, c1b = Z;
    v16i c2a = Z, c2b = Z, c3a = Z, c3b = Z;

    const u32 lhalf   = (u32)((lane >> 5) * 5440);
    const u32 rowbase = (u32)((4 * wm) * 544);
    const u32 bwoff   = (u32)(wn * 4096 + lane * 16);

    // preload A(phase 0): ksteps 0 (cb=0,dy=0,dx=0) and 1 (cb=1,dy=0,dx=0)
    v4i ea0, ea1, ea2, ea3, ea4, ea5, ea6, ea7;
    v4i oa0, oa1, oa2, oa3, oa4, oa5, oa6, oa7;
    {
        const u32 a0 = lhalf + rowbase + (u32)(col0 * 16);
        ea0 = *(const v4i*)(lds + a0);
        ea1 = *(const v4i*)(lds + a0 + 544);
        ea2 = *(const v4i*)(lds + a0 + 1088);
        ea3 = *(const v4i*)(lds + a0 + 1632);
        const u32 a1 = a0 + 10880;
        ea4 = *(const v4i*)(lds + a1);
        ea5 = *(const v4i*)(lds + a1 + 544);
        ea6 = *(const v4i*)(lds + a1 + 1088);
        ea7 = *(const v4i*)(lds + a1 + 1632);
    }

#define PHASE(PH, AC0,AC1,AC2,AC3,AC4,AC5,AC6,AC7,                              \
                  AN0,AN1,AN2,AN3,AN4,AN5,AN6,AN7)                              \
    {                                                                           \
        const int ph_ = (PH);                                                   \
        {   /* stage B(ph+2) -> ring slot (ph+2)&3 (wrapped source: unread) */  \
            int pf_ = ph_ + 2; if (pf_ >= 36) pf_ -= 36;                        \
            unsigned char* d_ = lds + 87040 + ((ph_ + 2) & 3) * 16384           \
                              + wn * 4096;                                      \
            const size_t k0_ = (size_t)(2 * pf_) << 10;                         \
            const size_t k1_ = (size_t)(2 * pf_ + 1) << 10;                     \
            glds16(bsrcA + k0_, d_);                                            \
            glds16(bsrcB + k0_, d_ + 1024);                                     \
            glds16(bsrcA + k1_, d_ + 2048);                                     \
            glds16(bsrcB + k1_, d_ + 3072);                                     \
        }                                                                       \
        asm volatile("s_waitcnt vmcnt(8)" ::: "memory");                        \
        __builtin_amdgcn_sched_barrier(0);                                      \
        const u32 bo_ = 87040u + (u32)((ph_ & 3) * 16384) + bwoff;              \
        const v4i bk0g0_ = *(const v4i*)(lds + bo_);                            \
        const v4i bk0g1_ = *(const v4i*)(lds + bo_ + 1024);                     \
        const v4i bk1g0_ = *(const v4i*)(lds + bo_ + 2048);                     \
        const v4i bk1g1_ = *(const v4i*)(lds + bo_ + 3072);                     \
        {   /* A(ph+1): ksteps 2ph+2, 2ph+3 */                                  \
            const int ka_ = 2 * ph_ + 2;                                        \
            const int cb0_ = ka_ & 7, p0_ = ka_ >> 3;                           \
            const int dy0_ = p0_ / 3, dx0_ = p0_ - dy0_ * 3;                    \
            const u32 ao0_ = lhalf + (u32)(cb0_ * 10880) + rowbase              \
                           + (u32)(dy0_ * 544) + (u32)((dx0_ + col0) * 16);     \
            AN0 = *(const v4i*)(lds + ao0_);                                    \
            AN1 = *(const v4i*)(lds + ao0_ + 544);                              \
            AN2 = *(const v4i*)(lds + ao0_ + 1088);                             \
            AN3 = *(const v4i*)(lds + ao0_ + 1632);                             \
            const int kb_ = ka_ + 1;                                            \
            const int cb1_ = kb_ & 7, p1_ = kb_ >> 3;                           \
            const int dy1_ = p1_ / 3, dx1_ = p1_ - dy1_ * 3;                    \
            const u32 ao1_ = lhalf + (u32)(cb1_ * 10880) + rowbase              \
                           + (u32)(dy1_ * 544) + (u32)((dx1_ + col0) * 16);     \
            AN4 = *(const v4i*)(lds + ao1_);                                    \
            AN5 = *(const v4i*)(lds + ao1_ + 544);                              \
            AN6 = *(const v4i*)(lds + ao1_ + 1088);                             \
            AN7 = *(const v4i*)(lds + ao1_ + 1632);                             \
        }                                                                       \
        __builtin_amdgcn_s_barrier();                                           \
        asm volatile("s_waitcnt lgkmcnt(8)" ::: "memory");                      \
        __builtin_amdgcn_sched_barrier(0);                                      \
        __builtin_amdgcn_s_setprio(1);                                          \
        c0a = MFMA_I8(AC0, bk0g0_, c0a);  c0b = MFMA_I8(AC0, bk0g1_, c0b);      \
        c1a = MFMA_I8(AC1, bk0g0_, c1a);  c1b = MFMA_I8(AC1, bk0g1_, c1b);      \
        c2a = MFMA_I8(AC2, bk0g0_, c2a);  c2b = MFMA_I8(AC2, bk0g1_, c2b);      \
        c3a = MFMA_I8(AC3, bk0g0_, c3a);  c3b = MFMA_I8(AC3, bk0g1_, c3b);      \
        c0a = MFMA_I8(AC4, bk1g0_, c0a);  c0b = MFMA_I8(AC4, bk1g1_, c0b);      \
        c1a = MFMA_I8(AC5, bk1g0_, c1a);  c1b = MFMA_I8(AC5, bk1g1_, c1b);      \
        c2a = MFMA_I8(AC6, bk1g0_, c2a);  c2b = MFMA_I8(AC6, bk1g1_, c2b);      \
        c3a = MFMA_I8(AC7, bk1g0_, c3a);  c3b = MFMA_I8(AC7, bk1g1_, c3b);      \
        __builtin_amdgcn_s_setprio(0);                                          \
        __builtin_amdgcn_s_barrier();                                           \
    }

#pragma unroll 1
    for (int j = 0; j < 18; ++j) {
        const int ph = j * 2;
        PHASE(ph,     ea0,ea1,ea2,ea3,ea4,ea5,ea6,ea7,
                      oa0,oa1,oa2,oa3,oa4,oa5,oa6,oa7)
        PHASE(ph + 1, oa0,oa1,oa2,oa3,oa4,oa5,oa6,oa7,
                      ea0,ea1,ea2,ea3,ea4,ea5,ea6,ea7)
    }
#undef PHASE

    if (CONV == 1) {
#define EP1(ACC, MR, GI, SC)                                                    \
        { _Pragma("unroll")                                                     \
          for (int reg = 0; reg < 16; ++reg) {                                  \
              const float t = __fadd_rn(__fmul_rn(__fmul_rn((float)ACC[reg],    \
                                        SC.x), SC.y), SC.z);                    \
              const u64 m = __ballot(t > 0.f);                                  \
              if (lane == 0) {                                                  \
                  const int x = (reg & 3) + 8 * (reg >> 2);                     \
                  const int row = y0 + 4 * wm + (MR);                           \
                  const size_t pb = (size_t)n * 1024 + row * 32 + x;            \
                  A_out[pb * 8 + (g0 + (GI))]       = (u32)m;                   \
                  A_out[(pb + 4) * 8 + (g0 + (GI))] = (u32)(m >> 32);           \
              } } }
        EP1(c0a, 0, 0, scA)  EP1(c0b, 0, 1, scB)
        EP1(c1a, 1, 0, scA)  EP1(c1b, 1, 1, scB)
        EP1(c2a, 2, 0, scA)  EP1(c2b, 2, 1, scB)
        EP1(c3a, 3, 0, scA)  EP1(c3b, 3, 1, scB)
#undef EP1
    } else {
        __syncthreads();
        float* ep = (float*)lds;            // ep[x][co], stride 257 (32.9 KB)
#define EP2PASS(CA, CB, R)                                                      \
        { if (wm == ((R) >> 2)) {                                               \
            _Pragma("unroll")                                                   \
            for (int reg = 0; reg < 16; ++reg) {                                \
                const int x = (reg & 3) + 8 * (reg >> 2) + 4 * (lane >> 5);     \
                ep[x * 257 + (g0 + 0) * 32 + col0] =                            \
                    __fadd_rn(__fmul_rn(__fmul_rn((float)CA[reg], scA.x),       \
                                        scA.y), scA.z);                         \
                ep[x * 257 + (g0 + 1) * 32 + col0] =                            \
                    __fadd_rn(__fmul_rn(__fmul_rn((float)CB[reg], scB.x),       \
                                        scB.y), scB.z);                         \
            } }                                                                 \
          __syncthreads();                                                      \
          {                                                                     \
              const int co = tid >> 1, xh = tid & 1;                            \
              const size_t gb = ((size_t)(n * 256 + co)) * 1024                 \
                              + (y0 + (R)) * 32 + xh * 16;                      \
              _Pragma("unroll")                                                 \
              for (int x4 = 0; x4 < 16; x4 += 4) {                              \
                  float4 rr;                                                    \
                  rr.x = ep[(xh * 16 + x4 + 0) * 257 + co];                     \
                  rr.y = ep[(xh * 16 + x4 + 1) * 257 + co];                     \
                  rr.z = ep[(xh * 16 + x4 + 2) * 257 + co];                     \
                  rr.w = ep[(xh * 16 + x4 + 3) * 257 + co];                     \
                  const float4 xv = *(const float4*)(X + gb + x4);              \
                  rr.x = fminf(1.f, fmaxf(-1.f, __fadd_rn(rr.x, xv.x)));        \
                  rr.y = fminf(1.f, fmaxf(-1.f, __fadd_rn(rr.y, xv.y)));        \
                  rr.z = fminf(1.f, fmaxf(-1.f, __fadd_rn(rr.z, xv.z)));        \
                  rr.w = fminf(1.f, fmaxf(-1.f, __fadd_rn(rr.w, xv.w)));        \
                  *(float4*)(OUT + gb + x4) = rr;                               \
              }                                                                 \
          }                                                                     \
          __syncthreads(); }
        EP2PASS(c0a, c0b, 0)
        EP2PASS(c1a, c1b, 1)
        EP2PASS(c2a, c2b, 2)
        EP2PASS(c3a, c3b, 3)
        EP2PASS(c0a, c0b, 4)
        EP2PASS(c1a, c1b, 5)
        EP2PASS(c2a, c2b, 6)
        EP2PASS(c3a, c3b, 7)
#undef EP2PASS
    }
}

// ---------------------------------------------------------------------------
extern "C" void kernel_launch(void* const* d_in, const int* in_sizes, int n_in,
                              void* d_out, int out_size, void* d_ws, size_t ws_size,
                              hipStream_t stream)
{
    const float* x   = (const float*)d_in[0];
    const float* w1  = (const float*)d_in[1];
    const float* al1 = (const float*)d_in[2];
    const float* g1  = (const float*)d_in[3];
    const float* b1  = (const float*)d_in[4];
    const float* m1  = (const float*)d_in[5];
    const float* v1  = (const float*)d_in[6];
    const float* w2  = (const float*)d_in[7];
    const float* al2 = (const float*)d_in[8];
    const float* g2  = (const float*)d_in[9];
    const float* b2  = (const float*)d_in[10];
    const float* m2  = (const float*)d_in[11];
    const float* v2  = (const float*)d_in[12];
    float* out = (float*)d_out;

    char* ws = (char*)d_ws;
    float4*        SC4  = (float4*)(ws);                        //   8 KB
    unsigned char* Wsgn = (unsigned char*)(ws + (64u << 10));   // 1.18 MB
    uint4*         Bf   = (uint4*)(ws + (2u << 20));            // 1.18 MB
    u32*           A1   = (u32*)(ws + (4u << 20));              // 2 MB
    u32*           A2   = (u32*)(ws + (6u << 20));              // 2 MB
    (void)ws_size; (void)in_sizes; (void)n_in; (void)out_size;

    prep_weights<<<dim3(256, 2), 256, 0, stream>>>(w1, w2, al1, g1, b1, m1, v1,
                                                   al2, g2, b2, m2, v2, Wsgn, SC4);
    build_bfrag<<<dim3(1152), 64, 0, stream>>>(Wsgn, Bf);
    binarize_x<<<dim3(512), 1024, 0, stream>>>(x, A1);
    conv_mfma<1><<<dim3(256), 512, 0, stream>>>(A1, (const v4i*)Bf, SC4,
                                                nullptr, A2, nullptr);
    conv_mfma<2><<<dim3(256), 512, 0, stream>>>(A2, (const v4i*)Bf, SC4,
                                                x, nullptr, out);
}

// Round 21
// 123.656 us; speedup vs baseline: 1.0468x; 1.0468x over previous
//
#include <hip/hip_runtime.h>
#include <cstdint>
#include <cstddef>

using u32 = unsigned int;
using u64 = unsigned long long;

typedef int v4i  __attribute__((ext_vector_type(4)));
typedef int v16i __attribute__((ext_vector_type(16)));

#define EPSV 1e-5f

// ---------------------------------------------------------------------------
// Kernel 1: weight prep. One block per (co, conv). 256 threads = 256 in-chans.
// Wsgn[conv][co][p][c] i8 = sign(w - mean); SC4 = (alpha, scale, shift, 0)
// with IEEE ops in the reference's exact order.
// ---------------------------------------------------------------------------
__global__ void prep_weights(const float* __restrict__ w1, const float* __restrict__ w2,
                             const float* __restrict__ a1, const float* __restrict__ g1,
                             const float* __restrict__ b1, const float* __restrict__ m1,
                             const float* __restrict__ v1,
                             const float* __restrict__ a2, const float* __restrict__ g2,
                             const float* __restrict__ b2, const float* __restrict__ m2,
                             const float* __restrict__ v2,
                             unsigned char* __restrict__ Wsgn, float4* __restrict__ SC4)
{
    const int co   = blockIdx.x;
    const int conv = blockIdx.y;
    const int c    = threadIdx.x;
    const float* w = conv ? w2 : w1;

    float wv[9];
    const float* wp = w + ((size_t)co * 256 + c) * 9;
    float s = 0.f;
#pragma unroll
    for (int p = 0; p < 9; ++p) { wv[p] = wp[p]; s += wv[p]; }

    __shared__ float red[256];
    red[c] = s;
    __syncthreads();
    for (int off = 128; off > 0; off >>= 1) {
        if (c < off) red[c] += red[c + off];
        __syncthreads();
    }
    const float mean = __fdiv_rn(red[0], 2304.0f);

    unsigned char* wrow = Wsgn + ((size_t)(conv * 256 + co) * 9) * 256;
#pragma unroll
    for (int p = 0; p < 9; ++p)
        wrow[p * 256 + c] = (wv[p] > mean) ? 0x01u : 0xFFu;

    if (c == 0) {
        const float alpha = conv ? a2[co] : a1[co];
        const float gamma = conv ? g2[co] : g1[co];
        const float beta  = conv ? b2[co] : b1[co];
        const float mu    = conv ? m2[co] : m1[co];
        const float var   = conv ? v2[co] : v1[co];
        const float sq    = __fsqrt_rn(__fadd_rn(var, EPSV));
        const float scale = __fdiv_rn(gamma, sq);
        const float shift = __fsub_rn(beta, __fdiv_rn(__fmul_rn(mu, gamma), sq));
        SC4[conv * 256 + co] = make_float4(alpha, scale, shift, 0.f);
    }
}

// ---------------------------------------------------------------------------
// Kernel 2: B fragments in exact mfma_i32_32x32x32_i8 operand order.
// Frag f = conv*576 + g*72 + p*8 + cb. Lane l: B[k=(l>>5)*16+j][n=l&31].
// ---------------------------------------------------------------------------
__global__ void build_bfrag(const unsigned char* __restrict__ Wsgn, uint4* __restrict__ Bf)
{
    const int f    = blockIdx.x;           // 0..1151
    const int lane = threadIdx.x;          // 0..63
    const int conv = f / 576;
    const int rem  = f % 576;
    const int g    = rem / 72;
    const int p    = (rem % 72) / 8;
    const int cb   = rem % 8;
    const int co   = g * 32 + (lane & 31);
    const unsigned char* src = Wsgn + ((size_t)(conv * 256 + co) * 9 + p) * 256
                                    + cb * 32 + (lane >> 5) * 16;
    Bf[(size_t)f * 64 + lane] = *(const uint4*)src;
}

// ---------------------------------------------------------------------------
// Kernel 3: binarize x -> packed bits. A[n][pixel][j], j = chan/32.
// ---------------------------------------------------------------------------
__global__ void binarize_x(const float* __restrict__ x, u32* __restrict__ A1)
{
    const int n = blockIdx.x >> 3;
    const int j = blockIdx.x & 7;
    const int p = threadIdx.x;
    const float* xp = x + (((size_t)n * 256 + j * 32) * 1024) + p;
    u32 bits = 0;
#pragma unroll
    for (int k = 0; k < 32; ++k) {
        float v = xp[(size_t)k * 1024];
        bits |= (v > 0.f ? 1u : 0u) << k;
    }
    A1[((size_t)n * 1024 + p) * 8 + j] = bits;
}

__device__ __forceinline__ u32 expand4(u32 x)
{
    u32 r;
    r  = ((x & 1u) ? 0x00000001u : 0x000000FFu);
    r |= ((x & 2u) ? 0x00000100u : 0x0000FF00u);
    r |= ((x & 4u) ? 0x00010000u : 0x00FF0000u);
    r |= ((x & 8u) ? 0x01000000u : 0xFF000000u);
    return r;
}

// ---------------------------------------------------------------------------
// Kernel 4/5: binary conv as i8 MFMA GEMM — FINAL (series best, R19 config).
//
// Series conclusion (R5-R20, eleven schedule variants): every spill-free
// structure — lockstep barriers, serial rolled, SSA dbuf, SB-pinned 1/2/4-
// deep pipelines, barrier-free wave-private rings with counted vmcnt,
// 8-phase raw-barrier schedules at 8 AND 16 MFMA per barrier-pair, 1-wave
// ILP interleave, 2-4 blocks/CU — lands at 60-74us/conv, MfmaUtil 21-25%.
// The ~1,600cyc/step residual stall is invariant to every source-level
// lever available; localizing it needs disasm-level iteration. Banking the
// measured best: R12 structure + XCD swizzle + lean pinning (R19 = 123.6us).
//
// Block: 256 thr = 4 waves; M=128 (4 rows x 32 cols), N=256 (all couts).
// Wave w: groups g0=2w,g1=2w+1 x 4 rows -> 8 v16i accs (128 AGPR).
// Grid 512; bijective XCD swizzle: logical = (wgid%8)*64 + wgid/8.
//
// LDS act tile [c16 16][r 0..5][xs 0..34), 16B cells = 52,224 B.
// granule%8 = xs%8 -> ds_read_b128 conflict-free (verified 0 all series).
// Step k (0..71): cb=k&7, p=k>>3 (dy=p/3,dx=p%3);
//   dso = labase + cb*6528 + dy*544 + dx*16; rows at +0/544/1088/1632.
// B: 4 named register pairs, refill-3-ahead in next step's load region;
// A: 1-step double buffer; 2 sched_barriers/step. Tail overruns land in
// mapped ws (never consumed).
//
// A: m(=x)=l&31, k=(l>>5)*16+j ; B: n(=co)=l&31 ; C/D: n=l&31,
// m=(reg&3)+8*(reg>>2)+4*(l>>5)   [HW-verified all series].
//
// CONV==1: t=(dot*alpha)*scale+shift; packed sign bits via __ballot.
// CONV==2: per-row LDS transpose ep[x][co] (pad 257) -> coalesced
//          clamp(t + X) float4 stores.
// ---------------------------------------------------------------------------
template<int CONV>
__global__ __launch_bounds__(256, 2)
void conv_mfma(const u32* __restrict__ A_in, const v4i* __restrict__ Bf,
               const float4* __restrict__ SC4, const float* __restrict__ X,
               u32* __restrict__ A_out, float* __restrict__ OUT)
{
    // bijective XCD swizzle: XCD = wgid%8 gets 64 consecutive logical blocks
    const int logical = (blockIdx.x & 7) * 64 + (blockIdx.x >> 3);
    const int n    = logical >> 3;
    const int yq   = logical & 7;
    const int y0   = yq * 4;
    const int tid  = threadIdx.x;
    const int wave = tid >> 6;
    const int lane = tid & 63;

    __shared__ alignas(16) unsigned char lds[52224];

    const int g0 = wave * 2, g1 = g0 + 1;
    const v4i* bp0 = Bf + ((size_t)(((CONV == 2) ? 576 : 0) + g0 * 72)) * 64 + lane;
    const v4i* bp1 = Bf + ((size_t)(((CONV == 2) ? 576 : 0) + g1 * 72)) * 64 + lane;

    // prologue B loads issued BEFORE staging (frags 0..2; W3 filled in-loop)
    v4i w00 = bp0[0],   w10 = bp1[0];
    v4i w01 = bp0[64],  w11 = bp1[64];
    v4i w02 = bp0[128], w12 = bp1[128];
    v4i w03 = w02,      w13 = w12;      // placeholder; refilled at step 0

    // ---- stage: packed bits -> i8 tile [c16][r 0..5][xs], halo -> 0 ----
    for (int s = tid; s < 3264; s += 256) {
        const int xs   = s % 34;
        const int rest = s / 34;
        const int r    = rest % 6;          // tile row (image row y0-1+r)
        const int c16  = rest / 6;          // 16-channel group
        const int iy   = y0 - 1 + r;
        const int ix   = xs - 1;
        u32 d0 = 0, d1 = 0, d2 = 0, d3 = 0;
        if ((unsigned)iy < 32u && (unsigned)ix < 32u) {
            const u32 wrd = A_in[((size_t)n * 1024 + iy * 32 + ix) * 8 + (c16 >> 1)];
            const u32 h = (wrd >> ((c16 & 1) * 16)) & 0xFFFFu;
            d0 = expand4(h);
            d1 = expand4(h >> 4);
            d2 = expand4(h >> 8);
            d3 = expand4(h >> 12);
        }
        *(uint4*)(lds + ((size_t)((c16 * 6 + r) * 34 + xs)) * 16) =
            make_uint4(d0, d1, d2, d3);
    }
    __syncthreads();

    const v16i Z  = {0,0,0,0,0,0,0,0,0,0,0,0,0,0,0,0};
    const v4i  Z4 = {0,0,0,0};
    v16i acc00 = Z, acc01 = Z;   // row y0   x {g0,g1}
    v16i acc10 = Z, acc11 = Z;   // row y0+1
    v16i acc20 = Z, acc21 = Z;   // row y0+2
    v16i acc30 = Z, acc31 = Z;   // row y0+3

    const u32 labase = (u32)((lane >> 5) * 3264 + (lane & 31) * 16);

#define SB  __builtin_amdgcn_sched_barrier(0)

#define DSOFFK(K)                                                               \
    (labase + (u32)(((K) & 7) * 6528 + ((((K) >> 3)) / 3) * 544                 \
                    + ((((K) >> 3)) % 3) * 16))

#define PREFA(A0, A1, A2, A3, DSO)                                              \
    A0 = *(const v4i*)(lds + (DSO));                                            \
    A1 = *(const v4i*)(lds + (DSO) + 544);                                      \
    A2 = *(const v4i*)(lds + (DSO) + 1088);                                     \
    A3 = *(const v4i*)(lds + (DSO) + 1632);

#define MFMA8(A0, A1, A2, A3, W0, W1)                                           \
    acc00 = __builtin_amdgcn_mfma_i32_32x32x32_i8(A0, W0, acc00, 0, 0, 0);      \
    acc01 = __builtin_amdgcn_mfma_i32_32x32x32_i8(A0, W1, acc01, 0, 0, 0);      \
    acc10 = __builtin_amdgcn_mfma_i32_32x32x32_i8(A1, W0, acc10, 0, 0, 0);      \
    acc11 = __builtin_amdgcn_mfma_i32_32x32x32_i8(A1, W1, acc11, 0, 0, 0);      \
    acc20 = __builtin_amdgcn_mfma_i32_32x32x32_i8(A2, W0, acc20, 0, 0, 0);      \
    acc21 = __builtin_amdgcn_mfma_i32_32x32x32_i8(A2, W1, acc21, 0, 0, 0);      \
    acc30 = __builtin_amdgcn_mfma_i32_32x32x32_i8(A3, W0, acc30, 0, 0, 0);      \
    acc31 = __builtin_amdgcn_mfma_i32_32x32x32_i8(A3, W1, acc31, 0, 0, 0);

    // A double-buffer sets
    v4i ea0 = Z4, ea1 = Z4, ea2 = Z4, ea3 = Z4;
    v4i oa0 = Z4, oa1 = Z4, oa2 = Z4, oa3 = Z4;

    PREFA(ea0, ea1, ea2, ea3, DSOFFK(0))

#pragma unroll 1
    for (int k4 = 0; k4 < 18; ++k4) {
        const int kb = k4 * 4;
        // step 0: refill W3<-frag kb+3 ; prefetch A(kb+1)->O ; MFMA E/W0
        w03 = bp0[3 * 64]; w13 = bp1[3 * 64];
        PREFA(oa0, oa1, oa2, oa3, DSOFFK(kb + 1)) SB;
        MFMA8(ea0, ea1, ea2, ea3, w00, w10) SB;
        // step 1: refill W0<-frag kb+4 ; prefetch A(kb+2)->E ; MFMA O/W1
        w00 = bp0[4 * 64]; w10 = bp1[4 * 64];
        PREFA(ea0, ea1, ea2, ea3, DSOFFK(kb + 2)) SB;
        MFMA8(oa0, oa1, oa2, oa3, w01, w11) SB;
        // step 2: refill W1<-frag kb+5 ; prefetch A(kb+3)->O ; MFMA E/W2
        w01 = bp0[5 * 64]; w11 = bp1[5 * 64];
        PREFA(oa0, oa1, oa2, oa3, DSOFFK(kb + 3)) SB;
        MFMA8(ea0, ea1, ea2, ea3, w02, w12) SB;
        // step 3: refill W2<-frag kb+6 ; prefetch A(kb+4)->E ; MFMA O/W3
        w02 = bp0[6 * 64]; w12 = bp1[6 * 64];
        PREFA(ea0, ea1, ea2, ea3, DSOFFK(kb + 4)) SB;
        MFMA8(oa0, oa1, oa2, oa3, w03, w13) SB;

        bp0 += 256; bp1 += 256;
    }
#undef DSOFFK
#undef PREFA
#undef MFMA8
#undef SB

    const int col = lane & 31;
    const float4 sc0 = SC4[((CONV == 2) ? 256 : 0) + g0 * 32 + col];
    const float4 sc1 = SC4[((CONV == 2) ? 256 : 0) + g1 * 32 + col];

    if (CONV == 1) {
#define EP1(ACC, RY, G, SC)                                                     \
        { _Pragma("unroll")                                                     \
          for (int reg = 0; reg < 16; ++reg) {                                  \
              const float t = __fadd_rn(__fmul_rn(__fmul_rn((float)ACC[reg],    \
                                        SC.x), SC.y), SC.z);                    \
              const u64 m = __ballot(t > 0.f);                                  \
              if (lane == 0) {                                                  \
                  const int x = (reg & 3) + 8 * (reg >> 2);                     \
                  const size_t pb = (size_t)n * 1024 + (y0 + (RY)) * 32 + x;    \
                  A_out[pb * 8 + (G)]       = (u32)m;                           \
                  A_out[(pb + 4) * 8 + (G)] = (u32)(m >> 32);                   \
              } } }
        EP1(acc00, 0, g0, sc0)  EP1(acc01, 0, g1, sc1)
        EP1(acc10, 1, g0, sc0)  EP1(acc11, 1, g1, sc1)
        EP1(acc20, 2, g0, sc0)  EP1(acc21, 2, g1, sc1)
        EP1(acc30, 3, g0, sc0)  EP1(acc31, 3, g1, sc1)
#undef EP1
    } else {
        __syncthreads();                    // act tile reads done
        float* ep = (float*)lds;            // ep[x][co] pad 257 = 32.9 KB
#define EP2PASS(A0, A1, RY)                                                     \
        { _Pragma("unroll")                                                     \
          for (int reg = 0; reg < 16; ++reg) {                                  \
              const int x = (reg & 3) + 8 * (reg >> 2) + 4 * (lane >> 5);       \
              const float t0 = __fadd_rn(__fmul_rn(__fmul_rn((float)A0[reg],    \
                                         sc0.x), sc0.y), sc0.z);                \
              const float t1 = __fadd_rn(__fmul_rn(__fmul_rn((float)A1[reg],    \
                                         sc1.x), sc1.y), sc1.z);                \
              ep[x * 257 + g0 * 32 + col] = t0;                                 \
              ep[x * 257 + g1 * 32 + col] = t1;                                 \
          }                                                                     \
          __syncthreads();                                                      \
          {                                                                     \
              const int co = tid;                                               \
              const size_t gb = ((size_t)(n * 256 + co)) * 1024                 \
                              + (y0 + (RY)) * 32;                               \
              _Pragma("unroll")                                                 \
              for (int x4 = 0; x4 < 32; x4 += 4) {                              \
                  float4 r;                                                     \
                  r.x = ep[(x4 + 0) * 257 + co];                                \
                  r.y = ep[(x4 + 1) * 257 + co];                                \
                  r.z = ep[(x4 + 2) * 257 + co];                                \
                  r.w = ep[(x4 + 3) * 257 + co];                                \
                  const float4 xv = *(const float4*)(X + gb + x4);              \
                  r.x = fminf(1.f, fmaxf(-1.f, __fadd_rn(r.x, xv.x)));          \
                  r.y = fminf(1.f, fmaxf(-1.f, __fadd_rn(r.y, xv.y)));          \
                  r.z = fminf(1.f, fmaxf(-1.f, __fadd_rn(r.z, xv.z)));          \
                  r.w = fminf(1.f, fmaxf(-1.f, __fadd_rn(r.w, xv.w)));          \
                  *(float4*)(OUT + gb + x4) = r;                                \
              }                                                                 \
          }                                                                     \
          __syncthreads(); }
        EP2PASS(acc00, acc01, 0)
        EP2PASS(acc10, acc11, 1)
        EP2PASS(acc20, acc21, 2)
        EP2PASS(acc30, acc31, 3)
#undef EP2PASS
    }
}

// ---------------------------------------------------------------------------
extern "C" void kernel_launch(void* const* d_in, const int* in_sizes, int n_in,
                              void* d_out, int out_size, void* d_ws, size_t ws_size,
                              hipStream_t stream)
{
    const float* x   = (const float*)d_in[0];
    const float* w1  = (const float*)d_in[1];
    const float* al1 = (const float*)d_in[2];
    const float* g1  = (const float*)d_in[3];
    const float* b1  = (const float*)d_in[4];
    const float* m1  = (const float*)d_in[5];
    const float* v1  = (const float*)d_in[6];
    const float* w2  = (const float*)d_in[7];
    const float* al2 = (const float*)d_in[8];
    const float* g2  = (const float*)d_in[9];
    const float* b2  = (const float*)d_in[10];
    const float* m2  = (const float*)d_in[11];
    const float* v2  = (const float*)d_in[12];
    float* out = (float*)d_out;

    char* ws = (char*)d_ws;
    float4*        SC4  = (float4*)(ws);                        //   8 KB
    unsigned char* Wsgn = (unsigned char*)(ws + (64u << 10));   // 1.18 MB
    uint4*         Bf   = (uint4*)(ws + (2u << 20));            // 1.18 MB (+overrun gap)
    u32*           A1   = (u32*)(ws + (4u << 20));              // 2 MB
    u32*           A2   = (u32*)(ws + (6u << 20));              // 2 MB
    (void)ws_size; (void)in_sizes; (void)n_in; (void)out_size;

    prep_weights<<<dim3(256, 2), 256, 0, stream>>>(w1, w2, al1, g1, b1, m1, v1,
                                                   al2, g2, b2, m2, v2, Wsgn, SC4);
    build_bfrag<<<dim3(1152), 64, 0, stream>>>(Wsgn, Bf);
    binarize_x<<<dim3(512), 1024, 0, stream>>>(x, A1);
    conv_mfma<1><<<dim3(512), 256, 0, stream>>>(A1, (const v4i*)Bf, SC4,
                                                nullptr, A2, nullptr);
    conv_mfma<2><<<dim3(512), 256, 0, stream>>>(A2, (const v4i*)Bf, SC4,
                                                x, nullptr, out);
}